// Round 1
// baseline (1019.002 us; speedup 1.0000x reference)
//
#include <hip/hip_runtime.h>
#include <hip/hip_bf16.h>

// GraphConv: out = verts@W0^T + b0 + scatter_sum_undirected(verts@W1^T + b1)
// V=100000, E=1000000, D=64. fp32 in/out; edges int64 (or int32) detected.
//
// R10 -> R11: fill_kernel was 87us at 18% HBM / 5.5% VALU — bound by 2M
// device-scope RETURNING atomicAdds (slot assignment) plus 92 MB of write
// amplification from scattered 4B col stores (RFO + eviction per entry).
// Replaced fill+gather+spill with count -> scan -> deterministic scatter ->
// bucket-local LDS accumulate:
//   hist:    per-block LDS histogram over 782 buckets (128 verts each),
//            plain stores to cntmat[bucket][block]. No returning atomics.
//   scan1:   exclusive scan across blocks within each bucket (one block/bucket).
//   scan2:   exclusive scan of bucket totals (single block).
//   scatter: re-scan edges; each (block,bucket) writes its private
//            pre-reserved run; slots via LDS atomics only. Packed u32
//            entries: n (17b) | t_local (7b) << 17. ~8 MB sequential-ish.
//   gather2: one block per bucket; acc[128][65] fp32 in LDS via ds_add_f32;
//            exact degree counted; writes sums + cnt. No CAP, no spill.
//   matvec:  unchanged MFMA [X|S] @ [W0;W1]^T.

#define NV 100000
#define NE 1000000
#define DIM 64
#define BSH 7                              // 128 vertices per bucket
#define NBUCK ((NV + 127) >> BSH)          // 782
#define NBLK 256                           // hist/scatter blocks
#define EPB ((NE + NBLK - 1) / NBLK)       // 3907 edges per block
#define NTILE (NV / 16)                    // 6250 MFMA row-tiles exactly

typedef __attribute__((ext_vector_type(8))) short short8;   // 8 bf16
typedef __attribute__((ext_vector_type(4))) float f32x4;

// ---------------------------------------------------------------------------
// Edge-layout detection. int64 words: [a_lo,a_hi,b_lo,b_hi,...], hi==0 always
// (0 <= idx < 100000). int32 words: [a0,b0,a1,b1,...], odd words random in
// [0,V). First 64 odd words all zero => int64 (FP prob ~ V^-64 ~ 0).
// ---------------------------------------------------------------------------
__global__ void detect_kernel(const int* __restrict__ edges, int* __restrict__ flag) {
    int v = edges[2 * threadIdx.x + 1];
    unsigned long long any = __ballot(v != 0);
    if (threadIdx.x == 0) *flag = (any == 0ull) ? 1 : 0;  // 1 = int64 layout
}

__device__ __forceinline__ unsigned f2bf1(float f) {  // RNE fp32 -> bf16 bits
    unsigned u = __float_as_uint(f);
    return (u + 0x7fffu + ((u >> 16) & 1u)) >> 16;
}

__device__ __forceinline__ short8 pack_bf8(float4 a, float4 b) {
    short8 r;
    r[0] = (short)f2bf1(a.x); r[1] = (short)f2bf1(a.y);
    r[2] = (short)f2bf1(a.z); r[3] = (short)f2bf1(a.w);
    r[4] = (short)f2bf1(b.x); r[5] = (short)f2bf1(b.y);
    r[6] = (short)f2bf1(b.z); r[7] = (short)f2bf1(b.w);
    return r;
}

// verts (fp32) -> vbf (bf16-packed rows, 2 features per uint, 128 B/row)
__global__ void prep_kernel(const float* __restrict__ verts, uint2* __restrict__ vbf) {
    long i = (long)blockIdx.x * blockDim.x + threadIdx.x;   // one float4 each
    if (i < (long)NV * (DIM / 4)) {
        float4 v = ((const float4*)verts)[i];
        uint2 w;
        w.x = f2bf1(v.x) | (f2bf1(v.y) << 16);
        w.y = f2bf1(v.z) | (f2bf1(v.w) << 16);
        vbf[i] = w;
    }
}

// ---------------------------------------------------------------------------
// Pass 1: per-block bucket histogram. LDS atomics only; one plain store per
// (bucket, block) cell. cntmat layout: [bucket][block] so scan1 is contiguous.
// ---------------------------------------------------------------------------
__global__ __launch_bounds__(256)
void hist_kernel(const int* __restrict__ edges, int* __restrict__ cntmat,
                 const int* __restrict__ flag) {
    __shared__ int hist[NBUCK];
    for (int k = threadIdx.x; k < NBUCK; k += 256) hist[k] = 0;
    __syncthreads();
    const bool is64 = (*flag != 0);
    const int eb = blockIdx.x * EPB;
    const int ee = min(NE, eb + EPB);
    for (int e = eb + threadIdx.x; e < ee; e += 256) {
        int a, b;
        if (is64) { int4 q = ((const int4*)edges)[e]; a = q.x; b = q.z; }
        else      { int2 q = ((const int2*)edges)[e]; a = q.x; b = q.y; }
        atomicAdd(&hist[a >> BSH], 1);
        atomicAdd(&hist[b >> BSH], 1);
    }
    __syncthreads();
    for (int k = threadIdx.x; k < NBUCK; k += 256)
        cntmat[k * NBLK + blockIdx.x] = hist[k];
}

// Exclusive scan of the 256 per-block counts within one bucket; total -> btot.
__global__ __launch_bounds__(256)
void scan1_kernel(int* __restrict__ cntmat, int* __restrict__ btot) {
    __shared__ int s[256];
    const int k = blockIdx.x, t = threadIdx.x;
    const int c = cntmat[k * NBLK + t];
    s[t] = c;
    __syncthreads();
    for (int off = 1; off < 256; off <<= 1) {
        int v = (t >= off) ? s[t - off] : 0;
        __syncthreads();
        s[t] += v;
        __syncthreads();
    }
    cntmat[k * NBLK + t] = s[t] - c;        // exclusive prefix within bucket
    if (t == 255) btot[k] = s[255];
}

// Exclusive scan of bucket totals (single block, Hillis-Steele over 1024 pad).
__global__ __launch_bounds__(256)
void scan2_kernel(const int* __restrict__ btot, int* __restrict__ bbase) {
    __shared__ int s[1024];
    const int t = threadIdx.x;
    for (int r = 0; r < 4; ++r) {
        int i = t + 256 * r;
        s[i] = (i < NBUCK) ? btot[i] : 0;
    }
    __syncthreads();
    for (int off = 1; off < 1024; off <<= 1) {
        int v[4];
        for (int r = 0; r < 4; ++r) {
            int i = t + 256 * r;
            v[r] = (i >= off) ? s[i - off] : 0;
        }
        __syncthreads();
        for (int r = 0; r < 4; ++r) s[t + 256 * r] += v[r];
        __syncthreads();
    }
    for (int r = 0; r < 4; ++r) {
        int i = t + 256 * r;
        if (i < NBUCK) bbase[i] = s[i] - btot[i];
    }
}

// ---------------------------------------------------------------------------
// Pass 2: deterministic scatter. Each block's run inside each bucket was
// pre-reserved by scan1/scan2, so slot assignment needs only LDS atomics.
// Entry packing: n (17 bits) | t_local (7 bits) << 17.
// ---------------------------------------------------------------------------
__global__ __launch_bounds__(256)
void scatter_kernel(const int* __restrict__ edges, const int* __restrict__ cntmat,
                    const int* __restrict__ bbase, unsigned* __restrict__ entries,
                    const int* __restrict__ flag) {
    __shared__ int cur[NBUCK];
    for (int k = threadIdx.x; k < NBUCK; k += 256)
        cur[k] = bbase[k] + cntmat[k * NBLK + blockIdx.x];
    __syncthreads();
    const bool is64 = (*flag != 0);
    const int eb = blockIdx.x * EPB;
    const int ee = min(NE, eb + EPB);
    for (int e = eb + threadIdx.x; e < ee; e += 256) {
        int a, b;
        if (is64) { int4 q = ((const int4*)edges)[e]; a = q.x; b = q.z; }
        else      { int2 q = ((const int2*)edges)[e]; a = q.x; b = q.y; }
        const int pa = atomicAdd(&cur[a >> BSH], 1);
        entries[pa] = (unsigned)b | ((unsigned)(a & 127) << 17);
        const int pb = atomicAdd(&cur[b >> BSH], 1);
        entries[pb] = (unsigned)a | ((unsigned)(b & 127) << 17);
    }
}

// ---------------------------------------------------------------------------
// Bucket-local gather: one block per bucket (128 vertices). acc in LDS fp32,
// ds_add_f32 accumulation; half-wave (32 lanes) per entry, 2 dims per lane.
// Row stride 65 floats => bank = (t + 2p) % 32, <=4-way (free-ish) on adds
// and conflict-free on the coalesced write-out.
// ---------------------------------------------------------------------------
__global__ __launch_bounds__(512)
void gather2_kernel(const uint2* __restrict__ vbf, const unsigned* __restrict__ entries,
                    const int* __restrict__ bbase, const int* __restrict__ btot,
                    float* __restrict__ sums, int* __restrict__ cnt) {
    __shared__ float acc[128 * 65];
    __shared__ int dcnt[128];
    const int tid = threadIdx.x;
    for (int i = tid; i < 128 * 65; i += 512) acc[i] = 0.f;
    if (tid < 128) dcnt[tid] = 0;
    __syncthreads();

    const int k = blockIdx.x;
    const int nE = btot[k];
    const int eb = bbase[k];
    const unsigned* vbfu = (const unsigned*)vbf;   // 32 uints per row
    const int lane = tid & 63;
    const int w = tid >> 6;                        // 8 waves
    const int half = lane >> 5;                    // which entry of a pair
    const int p = lane & 31;                       // dim pair (2p, 2p+1)

    for (int c = w * 64; c < nE; c += 512) {
        const unsigned my = (c + lane < nE) ? entries[eb + c + lane] : 0u;
        const int lim = min(64, nE - c);
        int j = 0;
        // 4 entries per step: both row loads issued before the LDS adds.
        for (; j + 4 <= lim; j += 4) {
            const unsigned e0 = __shfl(my, j + half, 64);
            const unsigned e1 = __shfl(my, j + 2 + half, 64);
            const unsigned w0 = vbfu[(long)(e0 & 0x1FFFF) * 32 + p];
            const unsigned w1 = vbfu[(long)(e1 & 0x1FFFF) * 32 + p];
            const int t0 = e0 >> 17, t1 = e1 >> 17;
            atomicAdd(&acc[t0 * 65 + 2 * p],     __uint_as_float(w0 << 16));
            atomicAdd(&acc[t0 * 65 + 2 * p + 1], __uint_as_float(w0 & 0xffff0000u));
            atomicAdd(&acc[t1 * 65 + 2 * p],     __uint_as_float(w1 << 16));
            atomicAdd(&acc[t1 * 65 + 2 * p + 1], __uint_as_float(w1 & 0xffff0000u));
            if (p == 0) { atomicAdd(&dcnt[t0], 1); atomicAdd(&dcnt[t1], 1); }
        }
        for (; j < lim; j += 2) {
            const int ei = j + half;
            const unsigned e0 = __shfl(my, ei, 64);
            if (ei < lim) {
                const unsigned w0 = vbfu[(long)(e0 & 0x1FFFF) * 32 + p];
                const int t0 = e0 >> 17;
                atomicAdd(&acc[t0 * 65 + 2 * p],     __uint_as_float(w0 << 16));
                atomicAdd(&acc[t0 * 65 + 2 * p + 1], __uint_as_float(w0 & 0xffff0000u));
                if (p == 0) atomicAdd(&dcnt[t0], 1);
            }
        }
    }
    __syncthreads();

    const int vb = k << BSH;
    const int nv = min(128, NV - vb);
    for (int i = tid; i < nv * DIM; i += 512) {
        const int t = i >> 6, d = i & 63;
        sums[(long)(vb + t) * DIM + d] = acc[t * 65 + d];
    }
    if (tid < nv) cnt[vb + tid] = dcnt[tid];
}

// ---------------------------------------------------------------------------
// MFMA matvec: out[V,64] = A(V x 128) @ Bw(128 x 64) + b0 + deg*b1, where
// A = [x_bf16 | s_bf16], Bw = [W0^T; W1^T]. mfma_f32_16x16x32_bf16:
//   A-frag:  lane holds A[m = lane&15][k = quad*8 + j]
//   B-frag:  lane holds B[k = quad*8 + j][n = lane&15]  (mirror of A)
//   C/D:     lane holds D[row = quad*4 + reg][col = lane&15]
// One wave per 16-vertex tile; 16 B-frags hoisted (weights, L2-hot).
// ---------------------------------------------------------------------------
__global__ __launch_bounds__(256)
void matvec_mfma_kernel(const uint2* __restrict__ vbf,
                        const float* __restrict__ sums,
                        const float* __restrict__ w0,
                        const float* __restrict__ b0,
                        const float* __restrict__ w1,
                        const float* __restrict__ b1,
                        const int* __restrict__ cnt,
                        float* __restrict__ out) {
    const int lane = threadIdx.x & 63;
    const int quad = lane >> 4;
    const int n = lane & 15;
    const int wave = (int)((blockIdx.x * blockDim.x + threadIdx.x) >> 6);
    const int nwaves = (int)((gridDim.x * blockDim.x) >> 6);

    // Hoist 16 B-fragments: B[c][t], c = K-chunk (0,1: W0; 2,3: W1), t = col-tile.
    // B[k_g][n_g] = W[d = t*16+n][k = (c&1)*32 + quad*8 + j]  (y_d = sum_k W[d][k] A[k])
    short8 B[4][4];
#pragma unroll
    for (int c = 0; c < 4; ++c) {
        const float* wsrc = (c < 2) ? w0 : w1;
        const int kb = (c & 1) * 32 + quad * 8;
#pragma unroll
        for (int t = 0; t < 4; ++t) {
            const int d = t * 16 + n;
            const float4 p = *(const float4*)(wsrc + d * DIM + kb);
            const float4 q = *(const float4*)(wsrc + d * DIM + kb + 4);
            B[c][t] = pack_bf8(p, q);
        }
    }
    float bias0[4], bias1[4];
#pragma unroll
    for (int t = 0; t < 4; ++t) { bias0[t] = b0[t * 16 + n]; bias1[t] = b1[t * 16 + n]; }

    const short8* vb8 = (const short8*)vbf;    // 8 uint16 = 16 B per frag

    for (int tile = wave; tile < NTILE; tile += nwaves) {
        const int base = tile * 16;
        const long v = base + n;               // this lane's A row
        f32x4 acc[4] = {{0.f,0.f,0.f,0.f},{0.f,0.f,0.f,0.f},
                        {0.f,0.f,0.f,0.f},{0.f,0.f,0.f,0.f}};

        // K-chunks 0,1: x from vbf (already bf16; 16B aligned frag loads)
#pragma unroll
        for (int c = 0; c < 2; ++c) {
            const short8 A = vb8[v * 8 + c * 4 + quad];
#pragma unroll
            for (int t = 0; t < 4; ++t)
                acc[t] = __builtin_amdgcn_mfma_f32_16x16x32_bf16(A, B[c][t], acc[t], 0, 0, 0);
        }
        // K-chunks 2,3: s from fp32 sums, packed to bf16 in-flight
#pragma unroll
        for (int c = 2; c < 4; ++c) {
            const int kb = (c - 2) * 32 + quad * 8;
            const float4 p = *(const float4*)(sums + v * DIM + kb);
            const float4 q = *(const float4*)(sums + v * DIM + kb + 4);
            const short8 A = pack_bf8(p, q);
#pragma unroll
            for (int t = 0; t < 4; ++t)
                acc[t] = __builtin_amdgcn_mfma_f32_16x16x32_bf16(A, B[c][t], acc[t], 0, 0, 0);
        }
        // Epilogue: D[row=quad*4+reg][col=n] + b0[d] + deg*b1[d]
#pragma unroll
        for (int r = 0; r < 4; ++r) {
            const int row = base + quad * 4 + r;
            const float dg = (float)cnt[row];
#pragma unroll
            for (int t = 0; t < 4; ++t)
                out[(long)row * DIM + t * 16 + n] = acc[t][r] + fmaf(dg, bias1[t], bias0[t]);
        }
    }
}

// ==========================================================================

extern "C" void kernel_launch(void* const* d_in, const int* in_sizes, int n_in,
                              void* d_out, int out_size, void* d_ws, size_t ws_size,
                              hipStream_t stream) {
    const float* verts = (const float*)d_in[0];
    const int*   edges = (const int*)d_in[1];
    const float* w0_w  = (const float*)d_in[2];
    const float* w0_b  = (const float*)d_in[3];
    const float* w1_w  = (const float*)d_in[4];
    const float* w1_b  = (const float*)d_in[5];
    float* out = (float*)d_out;

    // Workspace: sums fp32 V*D | vbf bf16 V*D | entries 2E u32 | cntmat |
    // bbase | btot | cnt | flag. Everything fully written -> no memset.
    char* p = (char*)d_ws;
    float*    sums    = (float*)p;    p += (size_t)NV * DIM * 4;
    uint2*    vbf     = (uint2*)p;    p += (size_t)NV * DIM * 2;
    unsigned* entries = (unsigned*)p; p += (size_t)2 * NE * 4;
    int*      cntmat  = (int*)p;      p += (size_t)NBUCK * NBLK * 4;
    int*      bbase   = (int*)p;      p += ((size_t)NBUCK * 4 + 15) & ~(size_t)15;
    int*      btot    = (int*)p;      p += ((size_t)NBUCK * 4 + 15) & ~(size_t)15;
    int*      cnt     = (int*)p;      p += (size_t)NV * 4;
    int*      flag    = (int*)p;

    detect_kernel<<<1, 64, 0, stream>>>(edges, flag);
    prep_kernel<<<(NV * (DIM / 4) + 255) / 256, 256, 0, stream>>>(verts, vbf);
    hist_kernel<<<NBLK, 256, 0, stream>>>(edges, cntmat, flag);
    scan1_kernel<<<NBUCK, 256, 0, stream>>>(cntmat, btot);
    scan2_kernel<<<1, 256, 0, stream>>>(btot, bbase);
    scatter_kernel<<<NBLK, 256, 0, stream>>>(edges, cntmat, bbase, entries, flag);
    gather2_kernel<<<NBUCK, 512, 0, stream>>>(vbf, entries, bbase, btot, sums, cnt);
    // 6250 tiles, one per wave: 1563 blocks x 4 waves (grid-stride guard)
    matvec_mfma_kernel<<<1563, 256, 0, stream>>>(vbf, sums, w0_w, w0_b,
                                                 w1_w, w1_b, cnt, out);
}

// Round 2
// 214.002 us; speedup vs baseline: 4.7617x; 4.7617x over previous
//
#include <hip/hip_runtime.h>
#include <hip/hip_bf16.h>

// GraphConv: out = verts@W0^T + b0 + scatter_sum_undirected(verts@W1^T + b1)
// V=100000, E=1000000, D=64. fp32 in/out; edges int64 (or int32) detected.
//
// R11 -> R12: gather2 (per-bucket LDS-atomic accumulate) was 875us — latency
// bound (VALU 2%, HBM 1.8%): 6.2K waves with a serial shfl->load->ds_add
// chain vs R10's 100K independent waves. Fix: keep the atomic-free
// hist/scan/scatter CSR build, add a cheap per-bucket counting-sort
// (reorder) producing dense per-vertex adjacency, and restore R10's proven
// wave-per-vertex register-accumulate gather reading that CSR. No CAP, no
// spill, no memset; exact degrees.
//   hist:    per-block LDS histogram over 782 buckets (128 verts each).
//   scan1:   exclusive scan across 256 blocks within each bucket.
//   scan2:   exclusive scan of bucket totals (single block).
//   scatter: pre-reserved (block,bucket) runs; LDS atomics only.
//            Entry: n (17b) | t_local (7b) << 17.
//   reorder: per bucket: counting-sort entries -> adj (neighbor only),
//            vstart[v], cnt[v]. Two streaming reads + one L2-local write.
//   gather3: R10 gather structure on adj/vstart/cnt; any degree via 64-chunks.
//   matvec:  unchanged MFMA [X|S] @ [W0;W1]^T.

#define NV 100000
#define NE 1000000
#define DIM 64
#define BSH 7                              // 128 vertices per bucket
#define NBUCK ((NV + 127) >> BSH)          // 782
#define NBLK 256                           // hist/scatter blocks
#define EPB ((NE + NBLK - 1) / NBLK)       // 3907 edges per block
#define NTILE (NV / 16)                    // 6250 MFMA row-tiles exactly

typedef __attribute__((ext_vector_type(8))) short short8;   // 8 bf16
typedef __attribute__((ext_vector_type(4))) float f32x4;

// ---------------------------------------------------------------------------
// Edge-layout detection. int64 words: [a_lo,a_hi,b_lo,b_hi,...], hi==0 always
// (0 <= idx < 100000). int32 words: [a0,b0,a1,b1,...], odd words random in
// [0,V). First 64 odd words all zero => int64 (FP prob ~ V^-64 ~ 0).
// ---------------------------------------------------------------------------
__global__ void detect_kernel(const int* __restrict__ edges, int* __restrict__ flag) {
    int v = edges[2 * threadIdx.x + 1];
    unsigned long long any = __ballot(v != 0);
    if (threadIdx.x == 0) *flag = (any == 0ull) ? 1 : 0;  // 1 = int64 layout
}

__device__ __forceinline__ unsigned f2bf1(float f) {  // RNE fp32 -> bf16 bits
    unsigned u = __float_as_uint(f);
    return (u + 0x7fffu + ((u >> 16) & 1u)) >> 16;
}

__device__ __forceinline__ short8 pack_bf8(float4 a, float4 b) {
    short8 r;
    r[0] = (short)f2bf1(a.x); r[1] = (short)f2bf1(a.y);
    r[2] = (short)f2bf1(a.z); r[3] = (short)f2bf1(a.w);
    r[4] = (short)f2bf1(b.x); r[5] = (short)f2bf1(b.y);
    r[6] = (short)f2bf1(b.z); r[7] = (short)f2bf1(b.w);
    return r;
}

// verts (fp32) -> vbf (bf16-packed rows, 2 features per uint, 128 B/row)
__global__ void prep_kernel(const float* __restrict__ verts, uint2* __restrict__ vbf) {
    long i = (long)blockIdx.x * blockDim.x + threadIdx.x;   // one float4 each
    if (i < (long)NV * (DIM / 4)) {
        float4 v = ((const float4*)verts)[i];
        uint2 w;
        w.x = f2bf1(v.x) | (f2bf1(v.y) << 16);
        w.y = f2bf1(v.z) | (f2bf1(v.w) << 16);
        vbf[i] = w;
    }
}

// ---------------------------------------------------------------------------
// Pass 1: per-block bucket histogram. LDS atomics only; one plain store per
// (bucket, block) cell. cntmat layout: [bucket][block] so scan1 is contiguous.
// ---------------------------------------------------------------------------
__global__ __launch_bounds__(256)
void hist_kernel(const int* __restrict__ edges, int* __restrict__ cntmat,
                 const int* __restrict__ flag) {
    __shared__ int hist[NBUCK];
    for (int k = threadIdx.x; k < NBUCK; k += 256) hist[k] = 0;
    __syncthreads();
    const bool is64 = (*flag != 0);
    const int eb = blockIdx.x * EPB;
    const int ee = min(NE, eb + EPB);
    for (int e = eb + threadIdx.x; e < ee; e += 256) {
        int a, b;
        if (is64) { int4 q = ((const int4*)edges)[e]; a = q.x; b = q.z; }
        else      { int2 q = ((const int2*)edges)[e]; a = q.x; b = q.y; }
        atomicAdd(&hist[a >> BSH], 1);
        atomicAdd(&hist[b >> BSH], 1);
    }
    __syncthreads();
    for (int k = threadIdx.x; k < NBUCK; k += 256)
        cntmat[k * NBLK + blockIdx.x] = hist[k];
}

// Exclusive scan of the 256 per-block counts within one bucket; total -> btot.
__global__ __launch_bounds__(256)
void scan1_kernel(int* __restrict__ cntmat, int* __restrict__ btot) {
    __shared__ int s[256];
    const int k = blockIdx.x, t = threadIdx.x;
    const int c = cntmat[k * NBLK + t];
    s[t] = c;
    __syncthreads();
    for (int off = 1; off < 256; off <<= 1) {
        int v = (t >= off) ? s[t - off] : 0;
        __syncthreads();
        s[t] += v;
        __syncthreads();
    }
    cntmat[k * NBLK + t] = s[t] - c;        // exclusive prefix within bucket
    if (t == 255) btot[k] = s[255];
}

// Exclusive scan of bucket totals (single block, Hillis-Steele over 1024 pad).
__global__ __launch_bounds__(256)
void scan2_kernel(const int* __restrict__ btot, int* __restrict__ bbase) {
    __shared__ int s[1024];
    const int t = threadIdx.x;
    for (int r = 0; r < 4; ++r) {
        int i = t + 256 * r;
        s[i] = (i < NBUCK) ? btot[i] : 0;
    }
    __syncthreads();
    for (int off = 1; off < 1024; off <<= 1) {
        int v[4];
        for (int r = 0; r < 4; ++r) {
            int i = t + 256 * r;
            v[r] = (i >= off) ? s[i - off] : 0;
        }
        __syncthreads();
        for (int r = 0; r < 4; ++r) s[t + 256 * r] += v[r];
        __syncthreads();
    }
    for (int r = 0; r < 4; ++r) {
        int i = t + 256 * r;
        if (i < NBUCK) bbase[i] = s[i] - btot[i];
    }
}

// ---------------------------------------------------------------------------
// Pass 2: deterministic scatter. Each block's run inside each bucket was
// pre-reserved by scan1/scan2, so slot assignment needs only LDS atomics.
// Entry packing: n (17 bits) | t_local (7 bits) << 17.
// ---------------------------------------------------------------------------
__global__ __launch_bounds__(256)
void scatter_kernel(const int* __restrict__ edges, const int* __restrict__ cntmat,
                    const int* __restrict__ bbase, unsigned* __restrict__ entries,
                    const int* __restrict__ flag) {
    __shared__ int cur[NBUCK];
    for (int k = threadIdx.x; k < NBUCK; k += 256)
        cur[k] = bbase[k] + cntmat[k * NBLK + blockIdx.x];
    __syncthreads();
    const bool is64 = (*flag != 0);
    const int eb = blockIdx.x * EPB;
    const int ee = min(NE, eb + EPB);
    for (int e = eb + threadIdx.x; e < ee; e += 256) {
        int a, b;
        if (is64) { int4 q = ((const int4*)edges)[e]; a = q.x; b = q.z; }
        else      { int2 q = ((const int2*)edges)[e]; a = q.x; b = q.y; }
        const int pa = atomicAdd(&cur[a >> BSH], 1);
        entries[pa] = (unsigned)b | ((unsigned)(a & 127) << 17);
        const int pb = atomicAdd(&cur[b >> BSH], 1);
        entries[pb] = (unsigned)a | ((unsigned)(b & 127) << 17);
    }
}

// ---------------------------------------------------------------------------
// Pass 3: per-bucket counting sort -> dense per-vertex CSR. One block per
// bucket. Reads its contiguous run twice (hist, place); writes adj into the
// same-size contiguous window (L2-local), plus vstart/cnt coalesced.
// ---------------------------------------------------------------------------
__global__ __launch_bounds__(256)
void reorder_kernel(const unsigned* __restrict__ entries,
                    const int* __restrict__ bbase, const int* __restrict__ btot,
                    unsigned* __restrict__ adj, int* __restrict__ vstart,
                    int* __restrict__ cnt) {
    __shared__ int h[128];
    __shared__ int pre[128];
    __shared__ int cur[128];
    const int k = blockIdx.x;
    const int nE = btot[k];
    const int eb = bbase[k];
    const int tid = threadIdx.x;
    if (tid < 128) h[tid] = 0;
    __syncthreads();
    for (int i = tid; i < nE; i += 256)
        atomicAdd(&h[entries[eb + i] >> 17], 1);
    __syncthreads();
    if (tid < 128) pre[tid] = h[tid];
    __syncthreads();
    for (int off = 1; off < 128; off <<= 1) {
        int v = (tid < 128 && tid >= off) ? pre[tid - off] : 0;
        __syncthreads();
        if (tid < 128) pre[tid] += v;
        __syncthreads();
    }
    if (tid < 128) {
        const int ex = pre[tid] - h[tid];   // exclusive prefix within bucket
        cur[tid] = ex;
        const int vb = (k << BSH) + tid;
        if (vb < NV) { vstart[vb] = eb + ex; cnt[vb] = h[tid]; }
    }
    __syncthreads();
    for (int i = tid; i < nE; i += 256) {
        const unsigned e = entries[eb + i];
        const int t = e >> 17;
        const int p = atomicAdd(&cur[t], 1);
        adj[eb + p] = e & 0x1FFFFu;
    }
}

// ---------------------------------------------------------------------------
// Gather (R10 structure): one wave per vertex; 4 rows in flight, register
// accumulate, shfl-broadcast of neighbor ids. Any degree via 64-chunks.
// ---------------------------------------------------------------------------
__device__ __forceinline__ void acc4(float4& a, uint2 w) {
    a.x += __uint_as_float(w.x << 16);
    a.y += __uint_as_float(w.x & 0xffff0000u);
    a.z += __uint_as_float(w.y << 16);
    a.w += __uint_as_float(w.y & 0xffff0000u);
}

__global__ __launch_bounds__(256)
void gather3_kernel(const uint2* __restrict__ vbf, const unsigned* __restrict__ adj,
                    const int* __restrict__ vstart, const int* __restrict__ cnt,
                    float* __restrict__ sums) {
    const int lane = threadIdx.x & 63;
    const int sub = lane & 15;
    const int grp = lane >> 4;
    const int v = (int)((blockIdx.x * blockDim.x + threadIdx.x) >> 6);
    if (v >= NV) return;

    const int dg = cnt[v];
    const int base = vstart[v];

    float4 a0 = {0.f, 0.f, 0.f, 0.f}, a1 = a0, a2 = a0, a3 = a0;
    for (int done = 0; done < dg; done += 64) {
        const int rem = dg - done;
        const int m = rem < 64 ? rem : 64;
        const int myc = (lane < m) ? (int)adj[base + done + lane] : 0;
        int j = 0;
        for (; j + 16 <= m; j += 16) {
            const int i0 = j + grp;
            const int c0 = __shfl(myc, i0, 64);
            const int c1 = __shfl(myc, i0 + 4, 64);
            const int c2 = __shfl(myc, i0 + 8, 64);
            const int c3 = __shfl(myc, i0 + 12, 64);
            const uint2 w0 = vbf[(long)c0 * 16 + sub];
            const uint2 w1 = vbf[(long)c1 * 16 + sub];
            const uint2 w2 = vbf[(long)c2 * 16 + sub];
            const uint2 w3 = vbf[(long)c3 * 16 + sub];
            acc4(a0, w0); acc4(a1, w1); acc4(a2, w2); acc4(a3, w3);
        }
#pragma unroll
        for (int t = 0; t < 4; ++t) {
            const int ii = j + grp + 4 * t;
            const int c = __shfl(myc, ii < 63 ? ii : 63, 64);
            if (ii < m) acc4(a0, vbf[(long)c * 16 + sub]);
        }
    }

    a0.x += (a1.x + a2.x) + a3.x;
    a0.y += (a1.y + a2.y) + a3.y;
    a0.z += (a1.z + a2.z) + a3.z;
    a0.w += (a1.w + a2.w) + a3.w;
    a0.x += __shfl_xor(a0.x, 16, 64); a0.y += __shfl_xor(a0.y, 16, 64);
    a0.z += __shfl_xor(a0.z, 16, 64); a0.w += __shfl_xor(a0.w, 16, 64);
    a0.x += __shfl_xor(a0.x, 32, 64); a0.y += __shfl_xor(a0.y, 32, 64);
    a0.z += __shfl_xor(a0.z, 32, 64); a0.w += __shfl_xor(a0.w, 32, 64);

    if (lane < 16) ((float4*)(sums + (long)v * DIM))[sub] = a0;
}

// ---------------------------------------------------------------------------
// MFMA matvec: out[V,64] = A(V x 128) @ Bw(128 x 64) + b0 + deg*b1, where
// A = [x_bf16 | s_bf16], Bw = [W0^T; W1^T]. mfma_f32_16x16x32_bf16:
//   A-frag:  lane holds A[m = lane&15][k = quad*8 + j]
//   B-frag:  lane holds B[k = quad*8 + j][n = lane&15]  (mirror of A)
//   C/D:     lane holds D[row = quad*4 + reg][col = lane&15]
// One wave per 16-vertex tile; 16 B-frags hoisted (weights, L2-hot).
// ---------------------------------------------------------------------------
__global__ __launch_bounds__(256)
void matvec_mfma_kernel(const uint2* __restrict__ vbf,
                        const float* __restrict__ sums,
                        const float* __restrict__ w0,
                        const float* __restrict__ b0,
                        const float* __restrict__ w1,
                        const float* __restrict__ b1,
                        const int* __restrict__ cnt,
                        float* __restrict__ out) {
    const int lane = threadIdx.x & 63;
    const int quad = lane >> 4;
    const int n = lane & 15;
    const int wave = (int)((blockIdx.x * blockDim.x + threadIdx.x) >> 6);
    const int nwaves = (int)((gridDim.x * blockDim.x) >> 6);

    // Hoist 16 B-fragments: B[c][t], c = K-chunk (0,1: W0; 2,3: W1), t = col-tile.
    // B[k_g][n_g] = W[d = t*16+n][k = (c&1)*32 + quad*8 + j]  (y_d = sum_k W[d][k] A[k])
    short8 B[4][4];
#pragma unroll
    for (int c = 0; c < 4; ++c) {
        const float* wsrc = (c < 2) ? w0 : w1;
        const int kb = (c & 1) * 32 + quad * 8;
#pragma unroll
        for (int t = 0; t < 4; ++t) {
            const int d = t * 16 + n;
            const float4 p = *(const float4*)(wsrc + d * DIM + kb);
            const float4 q = *(const float4*)(wsrc + d * DIM + kb + 4);
            B[c][t] = pack_bf8(p, q);
        }
    }
    float bias0[4], bias1[4];
#pragma unroll
    for (int t = 0; t < 4; ++t) { bias0[t] = b0[t * 16 + n]; bias1[t] = b1[t * 16 + n]; }

    const short8* vb8 = (const short8*)vbf;    // 8 uint16 = 16 B per frag

    for (int tile = wave; tile < NTILE; tile += nwaves) {
        const int base = tile * 16;
        const long v = base + n;               // this lane's A row
        f32x4 acc[4] = {{0.f,0.f,0.f,0.f},{0.f,0.f,0.f,0.f},
                        {0.f,0.f,0.f,0.f},{0.f,0.f,0.f,0.f}};

        // K-chunks 0,1: x from vbf (already bf16; 16B aligned frag loads)
#pragma unroll
        for (int c = 0; c < 2; ++c) {
            const short8 A = vb8[v * 8 + c * 4 + quad];
#pragma unroll
            for (int t = 0; t < 4; ++t)
                acc[t] = __builtin_amdgcn_mfma_f32_16x16x32_bf16(A, B[c][t], acc[t], 0, 0, 0);
        }
        // K-chunks 2,3: s from fp32 sums, packed to bf16 in-flight
#pragma unroll
        for (int c = 2; c < 4; ++c) {
            const int kb = (c - 2) * 32 + quad * 8;
            const float4 p = *(const float4*)(sums + v * DIM + kb);
            const float4 q = *(const float4*)(sums + v * DIM + kb + 4);
            const short8 A = pack_bf8(p, q);
#pragma unroll
            for (int t = 0; t < 4; ++t)
                acc[t] = __builtin_amdgcn_mfma_f32_16x16x32_bf16(A, B[c][t], acc[t], 0, 0, 0);
        }
        // Epilogue: D[row=quad*4+reg][col=n] + b0[d] + deg*b1[d]
#pragma unroll
        for (int r = 0; r < 4; ++r) {
            const int row = base + quad * 4 + r;
            const float dg = (float)cnt[row];
#pragma unroll
            for (int t = 0; t < 4; ++t)
                out[(long)row * DIM + t * 16 + n] = acc[t][r] + fmaf(dg, bias1[t], bias0[t]);
        }
    }
}

// ==========================================================================

extern "C" void kernel_launch(void* const* d_in, const int* in_sizes, int n_in,
                              void* d_out, int out_size, void* d_ws, size_t ws_size,
                              hipStream_t stream) {
    const float* verts = (const float*)d_in[0];
    const int*   edges = (const int*)d_in[1];
    const float* w0_w  = (const float*)d_in[2];
    const float* w0_b  = (const float*)d_in[3];
    const float* w1_w  = (const float*)d_in[4];
    const float* w1_b  = (const float*)d_in[5];
    float* out = (float*)d_out;

    // Workspace: sums | vbf | entries | adj | cntmat | vstart | cnt | bbase |
    // btot | flag. Everything fully written -> no memset.
    char* p = (char*)d_ws;
    float*    sums    = (float*)p;    p += (size_t)NV * DIM * 4;
    uint2*    vbf     = (uint2*)p;    p += (size_t)NV * DIM * 2;
    unsigned* entries = (unsigned*)p; p += (size_t)2 * NE * 4;
    unsigned* adj     = (unsigned*)p; p += (size_t)2 * NE * 4;
    int*      cntmat  = (int*)p;      p += (size_t)NBUCK * NBLK * 4;
    int*      vstart  = (int*)p;      p += (size_t)NV * 4;
    int*      cnt     = (int*)p;      p += (size_t)NV * 4;
    int*      bbase   = (int*)p;      p += ((size_t)NBUCK * 4 + 15) & ~(size_t)15;
    int*      btot    = (int*)p;      p += ((size_t)NBUCK * 4 + 15) & ~(size_t)15;
    int*      flag    = (int*)p;

    detect_kernel<<<1, 64, 0, stream>>>(edges, flag);
    prep_kernel<<<(NV * (DIM / 4) + 255) / 256, 256, 0, stream>>>(verts, vbf);
    hist_kernel<<<NBLK, 256, 0, stream>>>(edges, cntmat, flag);
    scan1_kernel<<<NBUCK, 256, 0, stream>>>(cntmat, btot);
    scan2_kernel<<<1, 256, 0, stream>>>(btot, bbase);
    scatter_kernel<<<NBLK, 256, 0, stream>>>(edges, cntmat, bbase, entries, flag);
    reorder_kernel<<<NBUCK, 256, 0, stream>>>(entries, bbase, btot, adj, vstart, cnt);
    gather3_kernel<<<(NV + 3) / 4, 256, 0, stream>>>(vbf, adj, vstart, cnt, sums);
    // 6250 tiles, one per wave: 1563 blocks x 4 waves (grid-stride guard)
    matvec_mfma_kernel<<<1563, 256, 0, stream>>>(vbf, sums, w0_w, w0_b,
                                                 w1_w, w1_b, cnt, out);
}

// Round 3
// 212.964 us; speedup vs baseline: 4.7849x; 1.0049x over previous
//
#include <hip/hip_runtime.h>
#include <hip/hip_bf16.h>

// GraphConv: out = verts@W0^T + b0 + scatter_sum_undirected(verts@W1^T + b1)
// V=100000, E=1000000, D=64. fp32 in/out; edges int64 (or int32) detected.
//
// R12 -> R13: gather3 (47.5us) was fetch-INVARIANT (same dur at 25MB and
// 101MB FETCH) => bound by its instruction stream (ds_bpermute shuffles +
// per-lane 64b address math + 8-op unpack/acc), not memory. But neighbor ids
// are WAVE-UNIFORM (one vertex per wave): gather5 forces them into SGPRs
// (readfirstlane -> s_load), reads each 128B row as global_load_ushort with
// scalar base + lane*2 (64 lanes x 2B = the row, ideally coalesced), and
// accumulates feature `lane` in ONE fp32 register: zero shuffles, zero
// cross-lane reduce, 2 VALU/visit. Sums are written as bf16 (sbf) directly
// (same rounding point as matvec's old in-flight pack -> bit-identical
// accuracy) saving 25.6MB store + 25.6MB read. detect folded into
// hist/scatter (per-wave self-detect); prep folded into hist tail.
//   hist(+prep): per-block LDS histogram over 782 buckets; prep grid-stride.
//   scan1/scan2: two-level exclusive scan of (bucket,block) counts.
//   scatter:     pre-reserved runs; LDS atomics only. n|t_local<<17.
//   reorder:     per-bucket counting sort -> dense adj + vstart + cnt.
//   gather5:     scalar-addressed wave-per-vertex accumulate -> sbf bf16.
//   matvec:      MFMA [X|S] @ [W0;W1]^T; A chunks 2,3 read sbf directly.

#define NV 100000
#define NE 1000000
#define DIM 64
#define BSH 7                              // 128 vertices per bucket
#define NBUCK ((NV + 127) >> BSH)          // 782
#define NBLK 256                           // hist/scatter blocks
#define EPB ((NE + NBLK - 1) / NBLK)       // 3907 edges per block
#define NTILE (NV / 16)                    // 6250 MFMA row-tiles exactly

typedef __attribute__((ext_vector_type(8))) short short8;   // 8 bf16
typedef __attribute__((ext_vector_type(4))) float f32x4;

// Per-wave edge-layout detection. int64 words: [a_lo,a_hi,...], hi==0 always
// (idx < 100000). int32 words: odd words random in [0,V). First 64 odd words
// all zero => int64 (FP prob ~ V^-64 ~ 0). Reads are L2-hot after first wave.
__device__ __forceinline__ bool detect_is64(const int* __restrict__ edges) {
    int v = edges[2 * (threadIdx.x & 63) + 1];
    return __ballot(v != 0) == 0ull;
}

__device__ __forceinline__ unsigned f2bf1(float f) {  // RNE fp32 -> bf16 bits
    unsigned u = __float_as_uint(f);
    return (u + 0x7fffu + ((u >> 16) & 1u)) >> 16;
}

__device__ __forceinline__ short8 pack_bf8(float4 a, float4 b) {
    short8 r;
    r[0] = (short)f2bf1(a.x); r[1] = (short)f2bf1(a.y);
    r[2] = (short)f2bf1(a.z); r[3] = (short)f2bf1(a.w);
    r[4] = (short)f2bf1(b.x); r[5] = (short)f2bf1(b.y);
    r[6] = (short)f2bf1(b.z); r[7] = (short)f2bf1(b.w);
    return r;
}

// ---------------------------------------------------------------------------
// Pass 1: per-block bucket histogram (LDS atomics only; plain stores to
// cntmat[bucket][block]) + fused prep (verts fp32 -> vbf bf16 rows, 128 B).
// ---------------------------------------------------------------------------
__global__ __launch_bounds__(256)
void hist_kernel(const int* __restrict__ edges, int* __restrict__ cntmat,
                 const float* __restrict__ verts, uint2* __restrict__ vbf) {
    __shared__ int hist[NBUCK];
    for (int k = threadIdx.x; k < NBUCK; k += 256) hist[k] = 0;
    const bool is64 = detect_is64(edges);
    __syncthreads();
    const int eb = blockIdx.x * EPB;
    const int ee = min(NE, eb + EPB);
    for (int e = eb + threadIdx.x; e < ee; e += 256) {
        int a, b;
        if (is64) { int4 q = ((const int4*)edges)[e]; a = q.x; b = q.z; }
        else      { int2 q = ((const int2*)edges)[e]; a = q.x; b = q.y; }
        atomicAdd(&hist[a >> BSH], 1);
        atomicAdd(&hist[b >> BSH], 1);
    }
    __syncthreads();
    for (int k = threadIdx.x; k < NBUCK; k += 256)
        cntmat[k * NBLK + blockIdx.x] = hist[k];

    // Fused prep: one float4 per iter -> uint2 (4 bf16). Independent of hist.
    const long np = (long)NV * (DIM / 4);
    for (long i = (long)blockIdx.x * 256 + threadIdx.x; i < np; i += 256L * NBLK) {
        float4 v = ((const float4*)verts)[i];
        uint2 w;
        w.x = f2bf1(v.x) | (f2bf1(v.y) << 16);
        w.y = f2bf1(v.z) | (f2bf1(v.w) << 16);
        vbf[i] = w;
    }
}

// Exclusive scan of the 256 per-block counts within one bucket; total -> btot.
__global__ __launch_bounds__(256)
void scan1_kernel(int* __restrict__ cntmat, int* __restrict__ btot) {
    __shared__ int s[256];
    const int k = blockIdx.x, t = threadIdx.x;
    const int c = cntmat[k * NBLK + t];
    s[t] = c;
    __syncthreads();
    for (int off = 1; off < 256; off <<= 1) {
        int v = (t >= off) ? s[t - off] : 0;
        __syncthreads();
        s[t] += v;
        __syncthreads();
    }
    cntmat[k * NBLK + t] = s[t] - c;        // exclusive prefix within bucket
    if (t == 255) btot[k] = s[255];
}

// Exclusive scan of bucket totals (single block, Hillis-Steele over 1024 pad).
__global__ __launch_bounds__(256)
void scan2_kernel(const int* __restrict__ btot, int* __restrict__ bbase) {
    __shared__ int s[1024];
    const int t = threadIdx.x;
    for (int r = 0; r < 4; ++r) {
        int i = t + 256 * r;
        s[i] = (i < NBUCK) ? btot[i] : 0;
    }
    __syncthreads();
    for (int off = 1; off < 1024; off <<= 1) {
        int v[4];
        for (int r = 0; r < 4; ++r) {
            int i = t + 256 * r;
            v[r] = (i >= off) ? s[i - off] : 0;
        }
        __syncthreads();
        for (int r = 0; r < 4; ++r) s[t + 256 * r] += v[r];
        __syncthreads();
    }
    for (int r = 0; r < 4; ++r) {
        int i = t + 256 * r;
        if (i < NBUCK) bbase[i] = s[i] - btot[i];
    }
}

// ---------------------------------------------------------------------------
// Pass 2: deterministic scatter. Each block's run inside each bucket was
// pre-reserved by scan1/scan2, so slot assignment needs only LDS atomics.
// Entry packing: n (17 bits) | t_local (7 bits) << 17.
// ---------------------------------------------------------------------------
__global__ __launch_bounds__(256)
void scatter_kernel(const int* __restrict__ edges, const int* __restrict__ cntmat,
                    const int* __restrict__ bbase, unsigned* __restrict__ entries) {
    __shared__ int cur[NBUCK];
    const bool is64 = detect_is64(edges);
    for (int k = threadIdx.x; k < NBUCK; k += 256)
        cur[k] = bbase[k] + cntmat[k * NBLK + blockIdx.x];
    __syncthreads();
    const int eb = blockIdx.x * EPB;
    const int ee = min(NE, eb + EPB);
    for (int e = eb + threadIdx.x; e < ee; e += 256) {
        int a, b;
        if (is64) { int4 q = ((const int4*)edges)[e]; a = q.x; b = q.z; }
        else      { int2 q = ((const int2*)edges)[e]; a = q.x; b = q.y; }
        const int pa = atomicAdd(&cur[a >> BSH], 1);
        entries[pa] = (unsigned)b | ((unsigned)(a & 127) << 17);
        const int pb = atomicAdd(&cur[b >> BSH], 1);
        entries[pb] = (unsigned)a | ((unsigned)(b & 127) << 17);
    }
}

// ---------------------------------------------------------------------------
// Pass 3: per-bucket counting sort -> dense per-vertex CSR. One block per
// bucket. Reads its contiguous run twice (hist, place); writes adj into the
// same-size contiguous window (L2-local), plus vstart/cnt coalesced.
// ---------------------------------------------------------------------------
__global__ __launch_bounds__(256)
void reorder_kernel(const unsigned* __restrict__ entries,
                    const int* __restrict__ bbase, const int* __restrict__ btot,
                    unsigned* __restrict__ adj, int* __restrict__ vstart,
                    int* __restrict__ cnt) {
    __shared__ int h[128];
    __shared__ int pre[128];
    __shared__ int cur[128];
    const int k = blockIdx.x;
    const int nE = btot[k];
    const int eb = bbase[k];
    const int tid = threadIdx.x;
    if (tid < 128) h[tid] = 0;
    __syncthreads();
    for (int i = tid; i < nE; i += 256)
        atomicAdd(&h[entries[eb + i] >> 17], 1);
    __syncthreads();
    if (tid < 128) pre[tid] = h[tid];
    __syncthreads();
    for (int off = 1; off < 128; off <<= 1) {
        int v = (tid < 128 && tid >= off) ? pre[tid - off] : 0;
        __syncthreads();
        if (tid < 128) pre[tid] += v;
        __syncthreads();
    }
    if (tid < 128) {
        const int ex = pre[tid] - h[tid];   // exclusive prefix within bucket
        cur[tid] = ex;
        const int vb = (k << BSH) + tid;
        if (vb < NV) { vstart[vb] = eb + ex; cnt[vb] = h[tid]; }
    }
    __syncthreads();
    for (int i = tid; i < nE; i += 256) {
        const unsigned e = entries[eb + i];
        const int t = e >> 17;
        const int p = atomicAdd(&cur[t], 1);
        adj[eb + p] = e & 0x1FFFFu;
    }
}

// ---------------------------------------------------------------------------
// Gather (scalar-addressed): one wave per vertex. Neighbor ids are wave-
// uniform -> SGPRs (s_load); each row read as global_load_ushort with scalar
// base + lane*2 (64 lanes x 2B = the 128B row). Lane L accumulates feature L
// in one fp32 register: no shuffles in the loop, no cross-lane reduce.
// Output written as bf16 (sbf) — the same rounding matvec applied anyway.
// ---------------------------------------------------------------------------
__global__ __launch_bounds__(256)
void gather5_kernel(const uint2* __restrict__ vbf, const unsigned* __restrict__ adj,
                    const int* __restrict__ vstart, const int* __restrict__ cnt,
                    unsigned* __restrict__ sbf) {
    const int lane = threadIdx.x & 63;
    int v = (int)((blockIdx.x * blockDim.x + threadIdx.x) >> 6);
    v = __builtin_amdgcn_readfirstlane(v);
    const int dg = __builtin_amdgcn_readfirstlane(cnt[v]);
    const int base = __builtin_amdgcn_readfirstlane(vstart[v]);
    const unsigned* __restrict__ ap = adj + base;
    const unsigned short* __restrict__ vb = (const unsigned short*)vbf;

    float a0 = 0.f, a1 = 0.f, a2 = 0.f, a3 = 0.f;
    int done = 0;
    for (; done + 8 <= dg; done += 8) {
        const int i0 = __builtin_amdgcn_readfirstlane((int)ap[done + 0]);
        const int i1 = __builtin_amdgcn_readfirstlane((int)ap[done + 1]);
        const int i2 = __builtin_amdgcn_readfirstlane((int)ap[done + 2]);
        const int i3 = __builtin_amdgcn_readfirstlane((int)ap[done + 3]);
        const int i4 = __builtin_amdgcn_readfirstlane((int)ap[done + 4]);
        const int i5 = __builtin_amdgcn_readfirstlane((int)ap[done + 5]);
        const int i6 = __builtin_amdgcn_readfirstlane((int)ap[done + 6]);
        const int i7 = __builtin_amdgcn_readfirstlane((int)ap[done + 7]);
        const float x0 = __uint_as_float((unsigned)vb[(size_t)i0 * 64 + lane] << 16);
        const float x1 = __uint_as_float((unsigned)vb[(size_t)i1 * 64 + lane] << 16);
        const float x2 = __uint_as_float((unsigned)vb[(size_t)i2 * 64 + lane] << 16);
        const float x3 = __uint_as_float((unsigned)vb[(size_t)i3 * 64 + lane] << 16);
        const float x4 = __uint_as_float((unsigned)vb[(size_t)i4 * 64 + lane] << 16);
        const float x5 = __uint_as_float((unsigned)vb[(size_t)i5 * 64 + lane] << 16);
        const float x6 = __uint_as_float((unsigned)vb[(size_t)i6 * 64 + lane] << 16);
        const float x7 = __uint_as_float((unsigned)vb[(size_t)i7 * 64 + lane] << 16);
        a0 += x0; a1 += x1; a2 += x2; a3 += x3;
        a0 += x4; a1 += x5; a2 += x6; a3 += x7;
    }
    for (; done < dg; ++done) {
        const int i0 = __builtin_amdgcn_readfirstlane((int)ap[done]);
        a0 += __uint_as_float((unsigned)vb[(size_t)i0 * 64 + lane] << 16);
    }
    const float acc = (a0 + a1) + (a2 + a3);
    const unsigned mb = f2bf1(acc);
    const unsigned nb = __shfl_down(mb, 1, 64);
    if (!(lane & 1)) sbf[(size_t)v * 32 + (lane >> 1)] = mb | (nb << 16);
}

// ---------------------------------------------------------------------------
// MFMA matvec: out[V,64] = A(V x 128) @ Bw(128 x 64) + b0 + deg*b1, where
// A = [x_bf16 | s_bf16], Bw = [W0^T; W1^T]. mfma_f32_16x16x32_bf16:
//   A-frag:  lane holds A[m = lane&15][k = quad*8 + j]
//   B-frag:  lane holds B[k = quad*8 + j][n = lane&15]  (mirror of A)
//   C/D:     lane holds D[row = quad*4 + reg][col = lane&15]
// One wave per 16-vertex tile; 16 B-frags hoisted (weights, L2-hot).
// A chunks 0,1 read vbf; chunks 2,3 read sbf (both bf16 rows, 128 B).
// ---------------------------------------------------------------------------
__global__ __launch_bounds__(256)
void matvec_mfma_kernel(const uint2* __restrict__ vbf,
                        const unsigned* __restrict__ sbf,
                        const float* __restrict__ w0,
                        const float* __restrict__ b0,
                        const float* __restrict__ w1,
                        const float* __restrict__ b1,
                        const int* __restrict__ cnt,
                        float* __restrict__ out) {
    const int lane = threadIdx.x & 63;
    const int quad = lane >> 4;
    const int n = lane & 15;
    const int wave = (int)((blockIdx.x * blockDim.x + threadIdx.x) >> 6);
    const int nwaves = (int)((gridDim.x * blockDim.x) >> 6);

    // Hoist 16 B-fragments: B[c][t], c = K-chunk (0,1: W0; 2,3: W1), t = col-tile.
    // B[k_g][n_g] = W[d = t*16+n][k = (c&1)*32 + quad*8 + j]  (y_d = sum_k W[d][k] A[k])
    short8 B[4][4];
#pragma unroll
    for (int c = 0; c < 4; ++c) {
        const float* wsrc = (c < 2) ? w0 : w1;
        const int kb = (c & 1) * 32 + quad * 8;
#pragma unroll
        for (int t = 0; t < 4; ++t) {
            const int d = t * 16 + n;
            const float4 p = *(const float4*)(wsrc + d * DIM + kb);
            const float4 q = *(const float4*)(wsrc + d * DIM + kb + 4);
            B[c][t] = pack_bf8(p, q);
        }
    }
    float bias0[4], bias1[4];
#pragma unroll
    for (int t = 0; t < 4; ++t) { bias0[t] = b0[t * 16 + n]; bias1[t] = b1[t * 16 + n]; }

    const short8* vb8 = (const short8*)vbf;    // 8 uint16 = 16 B per frag
    const short8* sb8 = (const short8*)sbf;

    for (int tile = wave; tile < NTILE; tile += nwaves) {
        const int base = tile * 16;
        const long v = base + n;               // this lane's A row
        f32x4 acc[4] = {{0.f,0.f,0.f,0.f},{0.f,0.f,0.f,0.f},
                        {0.f,0.f,0.f,0.f},{0.f,0.f,0.f,0.f}};

        // K-chunks 0,1: x rows from vbf
#pragma unroll
        for (int c = 0; c < 2; ++c) {
            const short8 A = vb8[v * 8 + c * 4 + quad];
#pragma unroll
            for (int t = 0; t < 4; ++t)
                acc[t] = __builtin_amdgcn_mfma_f32_16x16x32_bf16(A, B[c][t], acc[t], 0, 0, 0);
        }
        // K-chunks 2,3: s rows from sbf (already bf16)
#pragma unroll
        for (int c = 2; c < 4; ++c) {
            const short8 A = sb8[v * 8 + (c - 2) * 4 + quad];
#pragma unroll
            for (int t = 0; t < 4; ++t)
                acc[t] = __builtin_amdgcn_mfma_f32_16x16x32_bf16(A, B[c][t], acc[t], 0, 0, 0);
        }
        // Epilogue: D[row=quad*4+reg][col=n] + b0[d] + deg*b1[d]
#pragma unroll
        for (int r = 0; r < 4; ++r) {
            const int row = base + quad * 4 + r;
            const float dg = (float)cnt[row];
#pragma unroll
            for (int t = 0; t < 4; ++t)
                out[(long)row * DIM + t * 16 + n] = acc[t][r] + fmaf(dg, bias1[t], bias0[t]);
        }
    }
}

// ==========================================================================

extern "C" void kernel_launch(void* const* d_in, const int* in_sizes, int n_in,
                              void* d_out, int out_size, void* d_ws, size_t ws_size,
                              hipStream_t stream) {
    const float* verts = (const float*)d_in[0];
    const int*   edges = (const int*)d_in[1];
    const float* w0_w  = (const float*)d_in[2];
    const float* w0_b  = (const float*)d_in[3];
    const float* w1_w  = (const float*)d_in[4];
    const float* w1_b  = (const float*)d_in[5];
    float* out = (float*)d_out;

    // Workspace: vbf | sbf | entries | adj | cntmat | vstart | cnt | bbase |
    // btot. Everything fully written -> no memset.
    char* p = (char*)d_ws;
    uint2*    vbf     = (uint2*)p;    p += (size_t)NV * DIM * 2;
    unsigned* sbf     = (unsigned*)p; p += (size_t)NV * DIM * 2;
    unsigned* entries = (unsigned*)p; p += (size_t)2 * NE * 4;
    unsigned* adj     = (unsigned*)p; p += (size_t)2 * NE * 4;
    int*      cntmat  = (int*)p;      p += (size_t)NBUCK * NBLK * 4;
    int*      vstart  = (int*)p;      p += (size_t)NV * 4;
    int*      cnt     = (int*)p;      p += (size_t)NV * 4;
    int*      bbase   = (int*)p;      p += ((size_t)NBUCK * 4 + 15) & ~(size_t)15;
    int*      btot    = (int*)p;      p += ((size_t)NBUCK * 4 + 15) & ~(size_t)15;

    hist_kernel<<<NBLK, 256, 0, stream>>>(edges, cntmat, verts, vbf);
    scan1_kernel<<<NBUCK, 256, 0, stream>>>(cntmat, btot);
    scan2_kernel<<<1, 256, 0, stream>>>(btot, bbase);
    scatter_kernel<<<NBLK, 256, 0, stream>>>(edges, cntmat, bbase, entries);
    reorder_kernel<<<NBUCK, 256, 0, stream>>>(entries, bbase, btot, adj, vstart, cnt);
    gather5_kernel<<<NV / 4, 256, 0, stream>>>(vbf, adj, vstart, cnt, sbf);
    // 6250 tiles, one per wave: 1563 blocks x 4 waves (grid-stride guard)
    matvec_mfma_kernel<<<1563, 256, 0, stream>>>(vbf, sbf, w0_w, w0_b,
                                                 w1_w, w1_b, cnt, out);
}